// Round 1
// baseline (124.333 us; speedup 1.0000x reference)
//
#include <hip/hip_runtime.h>
#include <math.h>

// FedTGPClientLoss: fused CE (log-softmax gather) + prototype-MSE.
// B=16384, C=1000, D=512 (derived from in_sizes at launch).
// Stage 1: grid-stride over rows; per-row block reductions; per-block double
//          partial sums in d_ws (each slot written unconditionally -> no memset).
// Stage 2: single-block finalize, applies isfinite() semantics of the reference.

#ifndef INFINITY
#define INFINITY __builtin_inff()
#endif

#define NB_MAX 2048

__global__ __launch_bounds__(256) void fedtgp_rows(
    const float* __restrict__ logits,
    const int*   __restrict__ labels,
    const float* __restrict__ features,
    const float* __restrict__ protos,
    double* __restrict__ ce_part,
    double* __restrict__ pl_part,
    int B, int C, int D)
{
    const int tid  = threadIdx.x;
    const int lane = tid & 63;
    const int wv   = tid >> 6;

    __shared__ float rmax[4];
    __shared__ float rsum[4];
    __shared__ float rsq[4];

    const int C4 = C >> 2;   // 250
    const int D4 = D >> 2;   // 128

    double ce_acc = 0.0;
    double pl_acc = 0.0;

    for (int row = blockIdx.x; row < B; row += gridDim.x) {
        const int lab = labels[row];
        const float4* lrow4 = (const float4*)(logits + (size_t)row * C);

        // ---- pass 1: row max of logits (each thread holds <=1 float4) ----
        float4 lv = make_float4(0.f, 0.f, 0.f, 0.f);
        float m = -INFINITY;
        if (tid < C4) {
            lv = lrow4[tid];
            m = fmaxf(fmaxf(lv.x, lv.y), fmaxf(lv.z, lv.w));
        }
        #pragma unroll
        for (int off = 32; off > 0; off >>= 1)
            m = fmaxf(m, __shfl_xor(m, off, 64));
        if (lane == 0) rmax[wv] = m;
        __syncthreads();
        const float bmax = fmaxf(fmaxf(rmax[0], rmax[1]), fmaxf(rmax[2], rmax[3]));

        // ---- pass 2: sum exp(x - max) from registers ----
        float s = 0.f;
        if (tid < C4) {
            s = __expf(lv.x - bmax) + __expf(lv.y - bmax)
              + __expf(lv.z - bmax) + __expf(lv.w - bmax);
        }
        #pragma unroll
        for (int off = 32; off > 0; off >>= 1)
            s += __shfl_xor(s, off, 64);
        if (lane == 0) rsum[wv] = s;

        // ---- prototype MSE: sum (f - p)^2 over D ----
        float q = 0.f;
        if (tid < D4) {
            const float4 f = ((const float4*)(features + (size_t)row * D))[tid];
            const float4 p = ((const float4*)(protos   + (size_t)lab * D))[tid];
            const float dx = f.x - p.x, dy = f.y - p.y;
            const float dz = f.z - p.z, dw = f.w - p.w;
            q = dx*dx + dy*dy + dz*dz + dw*dw;
        }
        #pragma unroll
        for (int off = 32; off > 0; off >>= 1)
            q += __shfl_xor(q, off, 64);
        if (lane == 0) rsq[wv] = q;
        __syncthreads();

        if (tid == 0) {
            const float bsum = rsum[0] + rsum[1] + rsum[2] + rsum[3];
            const float bsq  = rsq[0]  + rsq[1]  + rsq[2]  + rsq[3];
            const float lse  = bmax + __logf(bsum);
            const float ce_b = lse - logits[(size_t)row * C + lab];
            ce_acc += (double)ce_b;
            pl_acc += (double)(bsq / (float)D);
        }
    }

    if (tid == 0) {
        ce_part[blockIdx.x] = ce_acc;
        pl_part[blockIdx.x] = pl_acc;
    }
}

__global__ __launch_bounds__(256) void fedtgp_finalize(
    const double* __restrict__ ce_part,
    const double* __restrict__ pl_part,
    float* __restrict__ out,
    int npart, double invB)
{
    const int tid  = threadIdx.x;
    const int lane = tid & 63;
    const int wv   = tid >> 6;
    __shared__ double rc[4];
    __shared__ double rp[4];

    double c = 0.0, p = 0.0;
    for (int i = tid; i < npart; i += 256) {
        c += ce_part[i];
        p += pl_part[i];
    }
    #pragma unroll
    for (int off = 32; off > 0; off >>= 1) {
        c += __shfl_xor(c, off, 64);
        p += __shfl_xor(p, off, 64);
    }
    if (lane == 0) { rc[wv] = c; rp[wv] = p; }
    __syncthreads();

    if (tid == 0) {
        const double cs = rc[0] + rc[1] + rc[2] + rc[3];
        const double ps = rp[0] + rp[1] + rp[2] + rp[3];
        float ce = (float)(cs * invB);
        float pl = (float)(ps * invB);
        if (!isfinite(ce)) ce = 0.0f;          // ce_loss = where(isfinite, ce, 0)
        float tot = ce + pl;                   // LAMDA = 1.0
        if (!isfinite(tot)) tot = ce;          // total = where(isfinite, total, ce)
        out[0] = tot;
        out[1] = ce;
        out[2] = pl;
    }
}

extern "C" void kernel_launch(void* const* d_in, const int* in_sizes, int n_in,
                              void* d_out, int out_size, void* d_ws, size_t ws_size,
                              hipStream_t stream)
{
    const float* logits   = (const float*)d_in[0];
    const int*   labels   = (const int*)  d_in[1];
    const float* features = (const float*)d_in[2];
    const float* protos   = (const float*)d_in[3];
    float* out = (float*)d_out;

    const int B = in_sizes[1];              // 16384
    const int C = in_sizes[0] / B;          // 1000
    const int D = in_sizes[2] / B;          // 512

    int nb = NB_MAX;
    // guard against a small workspace: need 2*nb doubles
    const size_t need_per_block = 2 * sizeof(double);
    if ((size_t)nb * need_per_block > ws_size) {
        nb = (int)(ws_size / need_per_block);
        if (nb < 1) nb = 1;
    }
    if (nb > B) nb = B;

    double* ce_part = (double*)d_ws;
    double* pl_part = ce_part + nb;

    fedtgp_rows<<<nb, 256, 0, stream>>>(logits, labels, features, protos,
                                        ce_part, pl_part, B, C, D);
    fedtgp_finalize<<<1, 256, 0, stream>>>(ce_part, pl_part, out, nb, 1.0 / (double)B);
}

// Round 2
// 121.638 us; speedup vs baseline: 1.0222x; 1.0222x over previous
//
#include <hip/hip_runtime.h>
#include <math.h>

// FedTGPClientLoss: fused CE (log-softmax gather) + prototype-MSE.
// B=16384, C=1000, D=512.
// R2 design: one WAVE per row (grid-stride), zero barriers in the row loop.
// Per lane: up to 4 float4 of the logits row cached in registers (4 loads in
// flight), online-softmax (m,s) state combined via 6-step wave butterfly.
// MSE: lane-strided float4 over D. Per-wave double partials -> per-block LDS
// combine (one barrier, at kernel end) -> tiny finalize block.

#ifndef INFINITY
#define INFINITY __builtin_inff()
#endif

#define NB 2048

__global__ __launch_bounds__(256) void fedtgp_rows(
    const float* __restrict__ logits,
    const int*   __restrict__ labels,
    const float* __restrict__ features,
    const float* __restrict__ protos,
    double* __restrict__ ce_part,
    double* __restrict__ pl_part,
    int B, int C, int D)
{
    const int tid  = threadIdx.x;
    const int lane = tid & 63;
    const int wv   = tid >> 6;
    const int gw     = blockIdx.x * 4 + wv;   // global wave id
    const int nwaves = gridDim.x * 4;

    const int C4   = C >> 2;
    const int Crem = C & 3;
    const int D4   = D >> 2;
    const int Drem = D & 3;

    double ce_acc = 0.0, pl_acc = 0.0;

    for (int row = gw; row < B; row += nwaves) {
        const float*  lrow = logits + (size_t)row * C;
        const float4* l4   = (const float4*)lrow;
        const int lab = labels[row];
        const float ll = lrow[lab];           // broadcast load (same addr all lanes)

        // ---- online softmax over the row, register-chunked (256 float4/chunk) ----
        float m = -INFINITY, s = 0.f;
        for (int base = 0; base < C4; base += 256) {
            float4 v[4];
            #pragma unroll
            for (int k = 0; k < 4; ++k) {
                const int idx = base + lane + 64 * k;
                v[k] = (idx < C4) ? l4[idx]
                                  : make_float4(-INFINITY, -INFINITY, -INFINITY, -INFINITY);
            }
            float cm = m;
            #pragma unroll
            for (int k = 0; k < 4; ++k)
                cm = fmaxf(cm, fmaxf(fmaxf(v[k].x, v[k].y), fmaxf(v[k].z, v[k].w)));
            if (cm > -INFINITY) {
                s *= __expf(m - cm);          // first chunk: m=-inf -> s stays 0
                #pragma unroll
                for (int k = 0; k < 4; ++k) {
                    s += __expf(v[k].x - cm) + __expf(v[k].y - cm)
                       + __expf(v[k].z - cm) + __expf(v[k].w - cm);
                }
                m = cm;
            }
        }
        if (Crem && lane < Crem) {            // scalar tail (unused for C=1000)
            const float x = lrow[(C4 << 2) + lane];
            const float cm = fmaxf(m, x);
            s = s * __expf(m - cm) + __expf(x - cm);
            m = cm;
        }

        // ---- prototype MSE: lane-strided float4 over D ----
        const float4* f4 = (const float4*)(features + (size_t)row * D);
        const float4* p4 = (const float4*)(protos   + (size_t)lab * D);
        float q = 0.f;
        for (int idx = lane; idx < D4; idx += 64) {
            const float4 f = f4[idx];
            const float4 p = p4[idx];
            const float dx = f.x - p.x, dy = f.y - p.y;
            const float dz = f.z - p.z, dw = f.w - p.w;
            q += dx * dx + dy * dy + dz * dz + dw * dw;
        }
        if (Drem && lane < Drem) {            // scalar tail (unused for D=512)
            const float df = features[(size_t)row * D + (D4 << 2) + lane]
                           - protos[(size_t)lab * D + (D4 << 2) + lane];
            q += df * df;
        }

        // ---- wave butterflies: (m,s) pair combine + q sum ----
        #pragma unroll
        for (int off = 32; off > 0; off >>= 1) {
            const float om = __shfl_xor(m, off, 64);
            const float os = __shfl_xor(s, off, 64);
            const float nm = fmaxf(m, om);
            s = s * __expf(m - nm) + os * __expf(om - nm);
            m = nm;
            q += __shfl_xor(q, off, 64);
        }

        if (lane == 0) {
            const float lse = m + __logf(s);
            ce_acc += (double)(lse - ll);
            pl_acc += (double)(q / (float)D);
        }
    }

    // ---- per-block combine (single barrier, once per kernel) ----
    __shared__ double sc[4], sp[4];
    if (lane == 0) { sc[wv] = ce_acc; sp[wv] = pl_acc; }
    __syncthreads();
    if (tid == 0) {
        ce_part[blockIdx.x] = sc[0] + sc[1] + sc[2] + sc[3];
        pl_part[blockIdx.x] = sp[0] + sp[1] + sp[2] + sp[3];
    }
}

__global__ __launch_bounds__(256) void fedtgp_finalize(
    const double* __restrict__ ce_part,
    const double* __restrict__ pl_part,
    float* __restrict__ out,
    int npart, double invB)
{
    const int tid  = threadIdx.x;
    const int lane = tid & 63;
    const int wv   = tid >> 6;
    __shared__ double rc[4];
    __shared__ double rp[4];

    double c = 0.0, p = 0.0;
    for (int i = tid; i < npart; i += 256) {
        c += ce_part[i];
        p += pl_part[i];
    }
    #pragma unroll
    for (int off = 32; off > 0; off >>= 1) {
        c += __shfl_xor(c, off, 64);
        p += __shfl_xor(p, off, 64);
    }
    if (lane == 0) { rc[wv] = c; rp[wv] = p; }
    __syncthreads();

    if (tid == 0) {
        const double cs = rc[0] + rc[1] + rc[2] + rc[3];
        const double ps = rp[0] + rp[1] + rp[2] + rp[3];
        float ce = (float)(cs * invB);
        float pl = (float)(ps * invB);
        if (!isfinite(ce)) ce = 0.0f;          // ce_loss = where(isfinite, ce, 0)
        float tot = ce + pl;                   // LAMDA = 1.0
        if (!isfinite(tot)) tot = ce;          // total = where(isfinite, total, ce)
        out[0] = tot;
        out[1] = ce;
        out[2] = pl;
    }
}

extern "C" void kernel_launch(void* const* d_in, const int* in_sizes, int n_in,
                              void* d_out, int out_size, void* d_ws, size_t ws_size,
                              hipStream_t stream)
{
    const float* logits   = (const float*)d_in[0];
    const int*   labels   = (const int*)  d_in[1];
    const float* features = (const float*)d_in[2];
    const float* protos   = (const float*)d_in[3];
    float* out = (float*)d_out;

    const int B = in_sizes[1];              // 16384
    const int C = in_sizes[0] / B;          // 1000
    const int D = in_sizes[2] / B;          // 512

    int nb = NB;
    const size_t need_per_block = 2 * sizeof(double);
    if ((size_t)nb * need_per_block > ws_size) {
        nb = (int)(ws_size / need_per_block);
        if (nb < 1) nb = 1;
    }

    double* ce_part = (double*)d_ws;
    double* pl_part = ce_part + nb;

    fedtgp_rows<<<nb, 256, 0, stream>>>(logits, labels, features, protos,
                                        ce_part, pl_part, B, C, D);
    fedtgp_finalize<<<1, 256, 0, stream>>>(ce_part, pl_part, out, nb, 1.0 / (double)B);
}

// Round 3
// 121.132 us; speedup vs baseline: 1.0264x; 1.0042x over previous
//
#include <hip/hip_runtime.h>
#include <math.h>

// FedTGPClientLoss: fused CE (log-softmax gather) + prototype-MSE.
// B=16384, C=1000, D=512.
// R3 design: ONE ROW PER WAVE (4096 blocks x 4 waves), zero barriers on the
// row path. All global loads issued up front per wave (4 float4 logits +
// 2 float4 features + 2 float4 protos = 8 KB/wave in flight). Per-lane local
// (max, sum-exp), then a single 6-step butterfly merging (m,s) AND the MSE
// partial q. Per-block partials (one barrier) -> 1-block finalize.

#ifndef INFINITY
#define INFINITY __builtin_inff()
#endif

__device__ __forceinline__ float safe_exp(float dm) {
    // exp(min(dm,0)): dm is always <= 0 mathematically; fmin also flushes the
    // NaN from (-inf) - (-inf) on fully-padded lanes to 0 -> exp=1, s=0 stays 0.
    return __expf(fminf(dm, 0.0f));
}

__global__ __launch_bounds__(256) void fedtgp_rows(
    const float* __restrict__ logits,
    const int*   __restrict__ labels,
    const float* __restrict__ features,
    const float* __restrict__ protos,
    double* __restrict__ ce_part,
    double* __restrict__ pl_part,
    int B, int C, int D)
{
    const int tid  = threadIdx.x;
    const int lane = tid & 63;
    const int wv   = tid >> 6;
    const int row  = blockIdx.x * 4 + wv;

    __shared__ double sc[4], sp[4];

    float ce_b = 0.f, pl_b = 0.f;
    bool valid = (row < B);

    if (valid) {
        const int   lab  = labels[row];
        const float* lrow = logits + (size_t)row * C;
        const int C4 = C >> 2;
        const int D4 = D >> 2;

        float m = -INFINITY;
        float s = 0.f;
        float q = 0.f;

        // ---- chunked register pass over logits (1 chunk for C<=1024) ----
        for (int base = 0; base < C4; base += 256) {
            const float4* l4 = (const float4*)lrow;
            float4 v[4];
            #pragma unroll
            for (int k = 0; k < 4; ++k) {
                const int idx = base + lane + 64 * k;
                v[k] = (idx < C4) ? l4[idx]
                                  : make_float4(-INFINITY, -INFINITY, -INFINITY, -INFINITY);
            }
            // features / protos / label-logit issued on first chunk so they
            // overlap the exp work below
            float cm = m;
            #pragma unroll
            for (int k = 0; k < 4; ++k)
                cm = fmaxf(cm, fmaxf(fmaxf(v[k].x, v[k].y), fmaxf(v[k].z, v[k].w)));
            s *= safe_exp(m - cm);
            #pragma unroll
            for (int k = 0; k < 4; ++k) {
                s += safe_exp(v[k].x - cm) + safe_exp(v[k].y - cm)
                   + safe_exp(v[k].z - cm) + safe_exp(v[k].w - cm);
            }
            m = cm;
        }
        // scalar tail (C % 4 != 0; unused for C=1000)
        for (int c = (C4 << 2) + lane; c < C; c += 64) {
            const float x  = lrow[c];
            const float cm = fmaxf(m, x);
            s = s * safe_exp(m - cm) + safe_exp(x - cm);
            m = cm;
        }

        // ---- prototype MSE: 2 float4 per lane (D=512), padded-zero safe ----
        {
            const float4* f4 = (const float4*)(features + (size_t)row * D);
            const float4* p4 = (const float4*)(protos   + (size_t)lab * D);
            #pragma unroll
            for (int k = 0; k < 2; ++k) {
                const int idx = lane + 64 * k;
                float4 f = make_float4(0.f, 0.f, 0.f, 0.f);
                float4 p = make_float4(0.f, 0.f, 0.f, 0.f);
                if (idx < D4) { f = f4[idx]; p = p4[idx]; }
                const float dx = f.x - p.x, dy = f.y - p.y;
                const float dz = f.z - p.z, dw = f.w - p.w;
                q += dx * dx + dy * dy + dz * dz + dw * dw;
            }
            for (int idx = lane + 128; idx < D4; idx += 64) {  // D>1024 fallback
                const float4 f = f4[idx];
                const float4 p = p4[idx];
                const float dx = f.x - p.x, dy = f.y - p.y;
                const float dz = f.z - p.z, dw = f.w - p.w;
                q += dx * dx + dy * dy + dz * dz + dw * dw;
            }
            for (int d = (D4 << 2) + lane; d < D; d += 64) {   // D%4 tail
                const float df = features[(size_t)row * D + d]
                               - protos[(size_t)lab * D + d];
                q += df * df;
            }
        }

        // ---- single butterfly: (m,s) pair-merge + q sum, 6 steps ----
        #pragma unroll
        for (int off = 32; off > 0; off >>= 1) {
            const float om = __shfl_xor(m, off, 64);
            const float os = __shfl_xor(s, off, 64);
            q += __shfl_xor(q, off, 64);
            const float nm = fmaxf(m, om);
            s = s * safe_exp(m - nm) + os * safe_exp(om - nm);
            m = nm;
        }

        const float ll  = lrow[lab];          // broadcast load
        const float lse = m + __logf(s);
        ce_b = lse - ll;
        pl_b = q / (float)D;
    }

    if (lane == 0) {
        sc[wv] = valid ? (double)ce_b : 0.0;
        sp[wv] = valid ? (double)pl_b : 0.0;
    }
    __syncthreads();
    if (tid == 0) {
        ce_part[blockIdx.x] = sc[0] + sc[1] + sc[2] + sc[3];
        pl_part[blockIdx.x] = sp[0] + sp[1] + sp[2] + sp[3];
    }
}

__global__ __launch_bounds__(1024) void fedtgp_finalize(
    const double* __restrict__ ce_part,
    const double* __restrict__ pl_part,
    float* __restrict__ out,
    int npart, double invB)
{
    const int tid  = threadIdx.x;
    const int lane = tid & 63;
    const int wv   = tid >> 6;
    __shared__ double rc[16];
    __shared__ double rp[16];

    double c = 0.0, p = 0.0;
    for (int i = tid; i < npart; i += 1024) {
        c += ce_part[i];
        p += pl_part[i];
    }
    #pragma unroll
    for (int off = 32; off > 0; off >>= 1) {
        c += __shfl_xor(c, off, 64);
        p += __shfl_xor(p, off, 64);
    }
    if (lane == 0) { rc[wv] = c; rp[wv] = p; }
    __syncthreads();

    if (tid == 0) {
        double cs = 0.0, ps = 0.0;
        #pragma unroll
        for (int k = 0; k < 16; ++k) { cs += rc[k]; ps += rp[k]; }
        float ce = (float)(cs * invB);
        float pl = (float)(ps * invB);
        if (!isfinite(ce)) ce = 0.0f;          // ce_loss = where(isfinite, ce, 0)
        float tot = ce + pl;                   // LAMDA = 1.0
        if (!isfinite(tot)) tot = ce;          // total = where(isfinite, total, ce)
        out[0] = tot;
        out[1] = ce;
        out[2] = pl;
    }
}

extern "C" void kernel_launch(void* const* d_in, const int* in_sizes, int n_in,
                              void* d_out, int out_size, void* d_ws, size_t ws_size,
                              hipStream_t stream)
{
    const float* logits   = (const float*)d_in[0];
    const int*   labels   = (const int*)  d_in[1];
    const float* features = (const float*)d_in[2];
    const float* protos   = (const float*)d_in[3];
    float* out = (float*)d_out;

    const int B = in_sizes[1];              // 16384
    const int C = in_sizes[0] / B;          // 1000
    const int D = in_sizes[2] / B;          // 512

    int nb = (B + 3) / 4;                   // one row per wave, 4 waves/block
    const size_t need_per_block = 2 * sizeof(double);
    if ((size_t)nb * need_per_block > ws_size) {
        nb = (int)(ws_size / need_per_block); // degenerate-guard; never hit here
        if (nb < 1) nb = 1;
    }

    double* ce_part = (double*)d_ws;
    double* pl_part = ce_part + nb;

    fedtgp_rows<<<nb, 256, 0, stream>>>(logits, labels, features, protos,
                                        ce_part, pl_part, B, C, D);
    fedtgp_finalize<<<1, 1024, 0, stream>>>(ce_part, pl_part, out, nb,
                                            1.0 / (double)B);
}